// Round 10
// baseline (2149.534 us; speedup 1.0000x reference)
//
#include <hip/hip_runtime.h>
#include <math.h>

#define N 2048
#define PSTRIDE 24
#define CCAP (1u << 20)
#define ECAP (1u << 19)
#define ELCAP 12288u  // edges cached in LDS (96KB)

typedef unsigned int uint;
typedef unsigned short ushort;
typedef unsigned long long ull;

// ws layout (bytes):
#define CTR_OFF   0        // ccnt@0, ecnt@64, mcount@128
#define PREP_OFF  256      // 2048*24 f32
#define CAND_OFF  196864   // u32[CCAP]
#define ETMP_OFF  4391168  // u64[ECAP]
#define ECSR_OFF  8585472  // u64[ECAP]
#define RINF_OFF  12779776 // u32[2048]
#define CUR_OFF   12787968 // u32[2048]
#define MARK_OFF  12796160 // u32[2048]
#define GCM_OFF   12804352 // u32[2048]
#define MLIST_OFF 12812544 // ushort[2048]
#define KOUT_OFF  12816640 // u64[2048]
#define NEED      12833024ull

// ---------- DPP wave-64 reductions (wave-uniform call sites ONLY) ----------
// row_shr 1/2/4/8 + row_bcast15/31; result read from lane 63.
__device__ __forceinline__ uint wave_umax_bcast(uint v) {
  int x = (int)v;
  int t;
  t = __builtin_amdgcn_update_dpp(0, x, 0x111, 0xF, 0xF, false); x = (int)((uint)x > (uint)t ? (uint)x : (uint)t);
  t = __builtin_amdgcn_update_dpp(0, x, 0x112, 0xF, 0xF, false); x = (int)((uint)x > (uint)t ? (uint)x : (uint)t);
  t = __builtin_amdgcn_update_dpp(0, x, 0x114, 0xF, 0xF, false); x = (int)((uint)x > (uint)t ? (uint)x : (uint)t);
  t = __builtin_amdgcn_update_dpp(0, x, 0x118, 0xF, 0xF, false); x = (int)((uint)x > (uint)t ? (uint)x : (uint)t);
  t = __builtin_amdgcn_update_dpp(0, x, 0x142, 0xF, 0xF, false); x = (int)((uint)x > (uint)t ? (uint)x : (uint)t);
  t = __builtin_amdgcn_update_dpp(0, x, 0x143, 0xF, 0xF, false); x = (int)((uint)x > (uint)t ? (uint)x : (uint)t);
  return (uint)__builtin_amdgcn_readlane(x, 63);
}

// Per-box precompute + zero counters/rowcnt/mark.
__global__ __launch_bounds__(256) void prep_kernel(const float* __restrict__ boxes,
                                                   float* __restrict__ prep,
                                                   uint* __restrict__ ctrs,
                                                   uint* __restrict__ rowcnt,
                                                   uint* __restrict__ mark) {
#pragma clang fp contract(off)
  int i = blockIdx.x * 256 + threadIdx.x;
  if (blockIdx.x == 0 && threadIdx.x < 3) ctrs[threadIdx.x * 16] = 0u;
  if (i >= N) return;
  rowcnt[i] = 0u;
  mark[i] = 0u;
  float xc = boxes[i * 5 + 0], yc = boxes[i * 5 + 1];
  float w = boxes[i * 5 + 2], h = boxes[i * 5 + 3], th = boxes[i * 5 + 4];
  float t = th * 0.017453292519943295f;
  float c = (float)cos((double)t);
  float s = (float)sin((double)t);
  float w2 = w * 0.5f, h2 = h * 0.5f;
  float lx[4] = {-w2, w2, w2, -w2};
  float ly[4] = {-h2, -h2, h2, h2};
  float* P = prep + i * PSTRIDE;
#pragma unroll
  for (int k = 0; k < 4; k++) {
    P[k * 2 + 0] = (xc + lx[k] * c) - ly[k] * s;
    P[k * 2 + 1] = (yc + lx[k] * s) + ly[k] * c;
  }
  P[8] = xc; P[9] = yc; P[10] = c; P[11] = s; P[12] = w2; P[13] = h2;
  P[14] = w * h;
  P[15] = sqrtf(w2 * w2 + h2 * h2);
  P[16] = w2 * fabsf(c) + h2 * fabsf(s) + 1e-4f;
  P[17] = w2 * fabsf(s) + h2 * fabsf(c) + 1e-4f;
}

// AABB IoU-upper-bound filter (conservative slack, bit-exact prune; proven r12).
__global__ __launch_bounds__(256) void cand_kernel(const float* __restrict__ prep,
                                                   uint* __restrict__ cand,
                                                   uint* __restrict__ ccnt) {
  uint gid = blockIdx.x * 256u + threadIdx.x;
  uint i = gid >> 11, j = gid & 2047u;
  const float* Pi = prep + i * PSTRIDE;
  const float* Pj = prep + j * PSTRIDE;
  float ox = (Pi[16] + Pj[16]) - fabsf(Pi[8] - Pj[8]);
  float oy = (Pi[17] + Pj[17]) - fabsf(Pi[9] - Pj[9]);
  bool keep = (i != j) && (ox > 0.0f) && (oy > 0.0f);
  if (keep) {
    float aa = Pi[14] + Pj[14];
    float iub = fminf(ox * oy, fminf(Pi[14], Pj[14]));
    keep = (13.0f * iub > 2.99f * aa);
  }
  ull m = __ballot(keep);
  if (m == 0ull) return;
  int lane = (int)(threadIdx.x & 63u);
  int leader = __ffsll((long long)m) - 1;
  uint base = 0;
  if (lane == leader) base = atomicAdd(ccnt, (uint)__popcll(m));
  base = (uint)__shfl((int)base, leader);
  if (keep) {
    uint pos = base + (uint)__popcll(m & ((1ull << lane) - 1ull));
    if (pos < CCAP) cand[pos] = (i << 11) | j;
  }
}

// Rotated-rect intersection weight — bit-exact fp32 mirror (proven r8-r12).
__device__ float pair_weight(const float* __restrict__ Pi, const float* __restrict__ Pj) {
#pragma clang fp contract(off)
  float ax[4], ay[4], bx[4], by[4];
#pragma unroll
  for (int k = 0; k < 4; k++) {
    ax[k] = Pi[2 * k]; ay[k] = Pi[2 * k + 1];
    bx[k] = Pj[2 * k]; by[k] = Pj[2 * k + 1];
  }
  float ptsx[24], ptsy[24];
  bool msk[24];
#pragma unroll
  for (int e = 0; e < 4; e++) {
    float Ax = ax[e], Ay = ay[e];
    float BAx = ax[(e + 1) & 3] - Ax, BAy = ay[(e + 1) & 3] - Ay;
#pragma unroll
    for (int f = 0; f < 4; f++) {
      float Cx = bx[f], Cy = by[f];
      float DCx = bx[(f + 1) & 3] - Cx, DCy = by[(f + 1) & 3] - Cy;
      float CAx = Cx - Ax, CAy = Cy - Ay;
      float den = BAx * DCy - BAy * DCx;
      bool dok = fabsf(den) > 1e-12f;
      float dens = dok ? den : 1.0f;
      float t = (CAx * DCy - CAy * DCx) / dens;
      float u = (CAx * BAy - CAy * BAx) / dens;
      int id = e * 4 + f;
      ptsx[id] = Ax + t * BAx;
      ptsy[id] = Ay + t * BAy;
      msk[id] = dok && (t >= 0.0f) && (t <= 1.0f) && (u >= 0.0f) && (u <= 1.0f);
    }
  }
  float xcj = Pj[8], ycj = Pj[9], cj = Pj[10], sj = Pj[11], w2j = Pj[12], h2j = Pj[13];
  float xci = Pi[8], yci = Pi[9], ci = Pi[10], si = Pi[11], w2i = Pi[12], h2i = Pi[13];
#pragma unroll
  for (int k = 0; k < 4; k++) {
    float dx = ax[k] - xcj, dy = ay[k] - ycj;
    float xl = dx * cj + dy * sj;
    float yl = -dx * sj + dy * cj;
    ptsx[16 + k] = ax[k]; ptsy[16 + k] = ay[k];
    msk[16 + k] = (fabsf(xl) <= w2j + 1e-5f) && (fabsf(yl) <= h2j + 1e-5f);
  }
#pragma unroll
  for (int k = 0; k < 4; k++) {
    float dx = bx[k] - xci, dy = by[k] - yci;
    float xl = dx * ci + dy * si;
    float yl = -dx * si + dy * ci;
    ptsx[20 + k] = bx[k]; ptsy[20 + k] = by[k];
    msk[20 + k] = (fabsf(xl) <= w2i + 1e-5f) && (fabsf(yl) <= h2i + 1e-5f);
  }
  int cnt = 0;
  float sx = 0.f, sy = 0.f;
#pragma unroll
  for (int k = 0; k < 24; k++) {
    if (msk[k]) { cnt++; sx += ptsx[k]; sy += ptsy[k]; }
  }
  float fc = (float)(cnt > 1 ? cnt : 1);
  float ctx = sx / fc, cty = sy / fc;
  float ang[32], px[32], py[32];
  int idp[32];
#pragma unroll
  for (int k = 0; k < 24; k++) {
    float rx = ptsx[k] - ctx, ry = ptsy[k] - cty;
    px[k] = rx; py[k] = ry; idp[k] = k;
    ang[k] = msk[k] ? (float)atan2((double)ry, (double)rx) : 1.0e3f;
  }
#pragma unroll
  for (int k = 24; k < 32; k++) { ang[k] = 1.0e30f; px[k] = 0.f; py[k] = 0.f; idp[k] = k; }
#pragma unroll
  for (int k = 2; k <= 32; k <<= 1) {
#pragma unroll
    for (int j = k >> 1; j > 0; j >>= 1) {
#pragma unroll
      for (int x = 0; x < 32; x++) {
        int l = x ^ j;
        if (l > x) {
          bool up = ((x & k) == 0);
          bool gt = (ang[x] > ang[l]) || (ang[x] == ang[l] && idp[x] > idp[l]);
          if (gt == up) {
            float t0 = ang[x]; ang[x] = ang[l]; ang[l] = t0;
            float t1 = px[x]; px[x] = px[l]; px[l] = t1;
            float t2 = py[x]; py[x] = py[l]; py[l] = t2;
            int t3 = idp[x]; idp[x] = idp[l]; idp[l] = t3;
          }
        }
      }
    }
  }
  float term[24];
#pragma unroll
  for (int x = 0; x < 24; x++) {
    int nx = (x + 1 < cnt) ? x + 1 : 0;
    float cr = px[x] * py[nx] - py[x] * px[nx];
    term[x] = (x < cnt) ? cr : 0.0f;
  }
  float r[8];
#pragma unroll
  for (int j = 0; j < 8; j++) r[j] = (term[j] + term[j + 8]) + term[j + 16];
  float ssum = ((r[0] + r[1]) + (r[2] + r[3])) + ((r[4] + r[5]) + (r[6] + r[7]));
  float area = 0.5f * fabsf(ssum);
  float inter = (cnt >= 3) ? area : 0.0f;
  float iou = inter / ((Pi[14] + Pj[14] - inter) + 1e-9f);
  return (iou > 0.3f) ? (1.0f - iou) : 1.0f;
}

// Heavy geometry on candidates (grid-stride); emit sparse edge iff w != 1.
// grid 4096: more resident waves/SIMD hide the dependent bitonic chain.
__global__ __launch_bounds__(64, 2) void weight_kernel(const float* __restrict__ prep,
                                                       const uint* __restrict__ cand,
                                                       const uint* __restrict__ ccnt,
                                                       ull* __restrict__ etmp,
                                                       uint* __restrict__ ecnt,
                                                       uint* __restrict__ rowcnt,
                                                       uint* __restrict__ mark) {
  uint n = *ccnt;
  if (n > CCAP) n = CCAP;
  for (uint idx = blockIdx.x * 64u + threadIdx.x; idx < n; idx += gridDim.x * 64u) {
    uint pk = cand[idx];
    uint i = pk >> 11, j = pk & 2047u;
    float w = pair_weight(prep + i * PSTRIDE, prep + j * PSTRIDE);
    if (w != 1.0f) {
      uint pos = atomicAdd(ecnt, 1u);
      if (pos < ECAP) {
        etmp[pos] = (((ull)__float_as_uint(w)) << 32) | (ull)pk;
        atomicAdd(rowcnt + i, 1u);
        mark[i] = 1u;
        mark[j] = 1u;
      }
    }
  }
}

// CSR finalize (proven r12).
__global__ __launch_bounds__(1024) void csr_fin(uint* __restrict__ rinfo,
                                                uint* __restrict__ cursor,
                                                const uint* __restrict__ mark,
                                                ushort* __restrict__ mlist,
                                                uint* __restrict__ gcm,
                                                uint* __restrict__ mcount) {
  __shared__ uint pre[N];
  __shared__ uint msh;
  int tid = threadIdx.x;
  uint c0 = rinfo[tid], c1 = rinfo[tid + 1024];
  pre[tid] = c0; pre[tid + 1024] = c1;
  if (tid == 0) msh = 0;
  __syncthreads();
  for (int d = 1; d < N; d <<= 1) {
    uint a0 = pre[tid] + ((tid >= d) ? pre[tid - d] : 0);
    uint a1 = pre[tid + 1024] + ((tid + 1024 >= d) ? pre[tid + 1024 - d] : 0);
    __syncthreads();
    pre[tid] = a0; pre[tid + 1024] = a1;
    __syncthreads();
  }
  uint p0 = pre[tid] - c0, p1 = pre[tid + 1024] - c1;
  rinfo[tid] = p0 | (c0 << 20);
  rinfo[tid + 1024] = p1 | (c1 << 20);
  cursor[tid] = p0;
  cursor[tid + 1024] = p1;
  if (mark[tid]) { uint m = atomicAdd(&msh, 1u); mlist[m] = (ushort)tid; gcm[tid] = m; }
  if (mark[tid + 1024]) { uint m = atomicAdd(&msh, 1u); mlist[m] = (ushort)(tid + 1024); gcm[tid + 1024] = m; }
  __syncthreads();
  if (tid == 0) *mcount = msh;
}

// Scatter edges into CSR slots; target stored as member index (grid-stride).
__global__ __launch_bounds__(256) void escat_kernel(const ull* __restrict__ etmp,
                                                    const uint* __restrict__ ecnt,
                                                    uint* __restrict__ cursor,
                                                    const uint* __restrict__ gcm,
                                                    ull* __restrict__ ecsr) {
  uint n = *ecnt;
  if (n > ECAP) n = ECAP;
  for (uint e = blockIdx.x * 256u + threadIdx.x; e < n; e += gridDim.x * 256u) {
    ull ed = etmp[e];
    uint lo = (uint)ed;
    uint i = (lo >> 11) & 2047u, j = lo & 2047u;
    uint pos = atomicAdd(cursor + i, 1u);
    ecsr[pos] = (ed & 0xFFFFFFFF00000000ull) | (ull)gcm[j];
  }
}

// Sequential soft-NMS over members, ONE wave — BATCHED selection, register
// walk with in-walk column seconds + PACKED KEYS (r10).
// Key = score<<32 | (2048-col)<<16 | osec<<15 | slot.  Tie order =
// (score, col, ...) — col determines the rest, so argmax tie-break matches
// the reference exactly.  readlane(lo) after the owner ballot yields col,
// slot AND osec => the per-accept readlane(ptop) and ballot(on_second) are
// GONE (cross-lane ops dominate the serial chain — r6/r8/r9 calibration).
// Rebuild tournament carries keys only (no slot arrays).  Cap 20 (batches
// are cap-bound: rounds ~ M/cap; bank-conflict counter tracks round count).
// Deferred apply (r6 structure; r7's eager pipeline regressed).
// Exactness:
//  - candidates are pre-batch column top-2; live candidate upper-bounds all
//    remaining current values of its column (decays deferred + only shrink).
//    g exact iff its slot untouched by an earlier accept's edges (register
//    ts ballot) — else break; re-surfaces exact next round.
//  - column whose SECOND is accepted is exhausted => batch ends after it.
//  - osec bit is set only in the promoted REGISTER copy (never stored), and
//    only perturbs ordering below the col field => ordering unchanged.
//  - apply in b-order; per-wave in-order DS pipe => per-slot multiply order
//    matches the reference exactly.
__global__ __launch_bounds__(64) void scan_sub(const float* __restrict__ scores,
                                               const ushort* __restrict__ mlist,
                                               const uint* __restrict__ mcount,
                                               const uint* __restrict__ rinfo_g,
                                               const ull* __restrict__ ecsr,
                                               const uint* __restrict__ ecnt,
                                               const uint* __restrict__ mark,
                                               ull* __restrict__ kout) {
#pragma clang fp contract(off)
  __shared__ ull mkey[N];       // column-major member keys: m -> (m&63)*32+(m>>6)
  __shared__ uint rinfo[N];
  __shared__ ull eld[ELCAP];
  const int lane = threadIdx.x;
#pragma unroll
  for (int k = 0; k < 8; k++) {
    int i4 = lane + 64 * k;
    ((uint4*)rinfo)[i4] = ((const uint4*)rinfo_g)[i4];
  }
#pragma unroll
  for (int k = 0; k < 32; k++) mkey[lane + 64 * k] = 0ull;
  // non-member keys straight to kout (output format: score<<32 | (2048-col))
#pragma unroll
  for (int k = 0; k < 32; k++) {
    int col = lane + 64 * k;
    if (!mark[col]) {
      uint b = __float_as_uint(scores[col]);
      kout[col] = (((ull)b) << 32) | (ull)(uint)(2048 - col);
    }
  }
  uint E = *ecnt;
  if (E > ECAP) E = ECAP;
  bool use_lds = (E <= ELCAP);
  if (use_lds) {
    uint n4 = (E + 1) >> 1;  // uint4 count
    for (uint q = (uint)lane; q < n4; q += 64u)
      ((uint4*)eld)[q] = ((const uint4*)ecsr)[q];
  }
  int M = (int)*mcount;
  // fill member keys, PACKED (rotated group order dodges the bank clash)
  for (int g = 0; g < 32; g++) {
    int gp = (g + lane) & 31;
    int m = lane + 64 * gp;
    if (m < M) {
      int col = (int)mlist[m];
      uint b = __float_as_uint(scores[col]);
      uint cm = (uint)lane * 32u + (uint)gp;  // CM(m) == slot
      uint lo = ((uint)(2048 - col) << 16) | cm;
      mkey[cm] = (((ull)b) << 32) | (ull)lo;
    }
  }
  asm volatile("s_waitcnt lgkmcnt(0) vmcnt(0)" ::: "memory");
  ull walk_pk = 0ull;   // lane's active candidate (column max, then second)
  ull wsec = 0ull;      // backup candidate (column second)
  uint myinfo = 0u;     // rinfo of active candidate's box
  uint minfo2 = 0u;     // rinfo of backup candidate's box
  auto rebuild = [&]() {
    const uint base = (uint)lane * 32u;
    ull m[16], s2[16];
#pragma unroll
    for (int k = 0; k < 16; k++) {
      uint i0 = base + (uint)((2 * k + lane) & 31);
      uint i1 = base + (uint)((2 * k + 1 + lane) & 31);
      ull a = mkey[i0], b = mkey[i1];
      bool gt = b > a;
      m[k] = gt ? b : a;
      s2[k] = gt ? a : b;
    }
#pragma unroll
    for (int st = 8; st >= 1; st >>= 1) {
#pragma unroll
      for (int k = 0; k < st; k++) {
        ull m1 = m[k], m2 = m[k + st];
        bool gt = m2 > m1;
        ull mw = gt ? m2 : m1;
        ull ml = gt ? m1 : m2;
        ull sa = s2[k], sb = s2[k + st];
        ull sm = sa > sb ? sa : sb;
        ull sec = ml > sm ? ml : sm;
        m[k] = mw; s2[k] = sec;
      }
    }
    walk_pk = m[0]; wsec = s2[0];
    int pb = 2048 - (int)((uint)walk_pk >> 16);
    myinfo = rinfo[((uint)pb <= 2047u) ? pb : 0];
    int pb2 = 2048 - (int)((uint)wsec >> 16);
    minfo2 = rinfo[((uint)pb2 <= 2047u) ? pb2 : 0];
  };
  rebuild();
  int tdone = 0;
  bool done = false;
  for (int round = 0; round < N; ++round) {
    if (done || tdone >= M) break;
    uint B = 0u;
    bool active = true;
    ull ew_[20];
    uint ts_[20], inf_[20];
    uint vmask = 0u;
#pragma unroll
    for (int b = 0; b < 20; b++) { ew_[b] = 0ull; ts_[b] = 0xFFFFFFFFu; inf_[b] = 0u; }
    // ---- WALK: up to 20 accepts; 32-bit fast-path argmax + lazy ts ----
#pragma unroll
    for (int b = 0; b < 20; b++) {
      if (active) {
        uint hi = (uint)(walk_pk >> 32);
        uint ghi = wave_umax_bcast(hi);
        // (double)score > 0.001  <=>  bits > 0x3A83126E for nonneg f32 in [0,1)
        if (!(ghi > 0x3A83126Eu)) {
          done = true; active = false;
        } else {
          ull bal = __ballot(hi == ghi);
          int ol; uint glo;
          if (__popcll(bal) == 1) {      // common: unique hi owner
            ol = __ffsll((long long)bal) - 1;
            glo = (uint)__builtin_amdgcn_readlane((int)(uint)walk_pk, ol);
          } else {                        // rare: exact lo tie-break
            uint cnd = (hi == ghi) ? (uint)walk_pk : 0u;
            glo = wave_umax_bcast(cnd);
            bal = __ballot((hi == ghi) && ((uint)walk_pk == glo));
            ol = __ffsll((long long)bal) - 1;
          }
          // lazy ts for accept b-1: edge data arrived during this reduction
          if (b > 0) {
            uint mtp = (uint)ew_[b - 1] & 2047u;
            ts_[b - 1] = ((mtp & 63u) << 5) | (mtp >> 6);
          }
          uint slot = glo & 0x7FFu;               // packed: no readlane needed
          bool osec = (glo & 0x8000u) != 0u;      // packed: no ballot needed
          uint info = (uint)__builtin_amdgcn_readlane((int)myinfo, ol);
          bool anyhit = false;
#pragma unroll
          for (int p = 0; p < 20; p++) {
            if (p < b) anyhit = anyhit || ((((vmask >> p) & 1u) != 0u) && (ts_[p] == slot));
          }
          if (__ballot(anyhit) != 0ull) {
            active = false;  // value stale-high; surfaces correctly next round
          } else {
            // ---- ACCEPT b ----
            uint oldlo = glo >> 16;               // 2048-col (osec/slot shifted out)
            int bj = 2048 - (int)oldlo;
            if (lane == 0) {
              kout[bj] = (((ull)ghi) << 32) | (ull)oldlo;
              mkey[slot] = 0ull;
            }
            if (lane == ol) {  // promote to column second; tag osec in-register
              walk_pk = wsec | 0x8000ull;
              myinfo = minfo2;
            }
            uint ptr = info & 0xFFFFFu;
            uint deg = info >> 20;
            bool vld = (uint)lane < deg;
            ull ed = 0ull;
            if (vld) ed = use_lds ? eld[ptr + (uint)lane] : ecsr[ptr + (uint)lane];
            ew_[b] = ed;      // ts computed lazily at next accept
            inf_[b] = info;
            vmask |= (vld ? 1u : 0u) << b;
            B = (uint)b + 1u;
            tdone++;
            if (deg > 64u) active = false;  // tail targets unchecked: end batch
            if (osec) active = false;       // column exhausted: end batch
          }
        }
      }
    }
    // ---- APPLY (bit-exact, b-order; DS in-order serializes shared slots) ----
#pragma unroll
    for (int b = 0; b < 20; b++) {
      if ((uint)b < B) {
        if ((vmask >> b) & 1u) {
          uint mt = (uint)ew_[b] & 2047u;
          uint ts = ((mt & 63u) << 5) | (mt >> 6);
          float w = __uint_as_float((uint)(ew_[b] >> 32));
          ull ok = mkey[ts];
          float nv = __uint_as_float((uint)(ok >> 32)) * w;
          mkey[ts] = (((ull)__float_as_uint(nv)) << 32) | (ok & 0xFFFFFFFFull);
        }
        uint ptr = inf_[b] & 0xFFFFFu, deg = inf_[b] >> 20;
        for (uint e = 64u + (uint)lane; e < deg; e += 64u) {
          ull ee = use_lds ? eld[ptr + e] : ecsr[ptr + e];
          uint mt = (uint)ee & 2047u;
          uint ts = ((mt & 63u) << 5) | (mt >> 6);
          float w = __uint_as_float((uint)(ee >> 32));
          ull ok = mkey[ts];
          float nv = __uint_as_float((uint)(ok >> 32)) * w;
          mkey[ts] = (((ull)__float_as_uint(nv)) << 32) | (ok & 0xFFFFFFFFull);
        }
      }
    }
    if (done || tdone >= M) break;
    asm volatile("s_waitcnt lgkmcnt(0)" ::: "memory");
    rebuild();
  }
  asm volatile("s_waitcnt lgkmcnt(0)" ::: "memory");
  // flush remaining (unselected) members; unpack col, emit output format
#pragma unroll
  for (int g = 0; g < 32; g++) {
    ull key = mkey[lane + 64 * g];
    if (key != 0ull) {
      uint oldlo = (uint)key >> 16;  // 2048-col
      int col = 2048 - (int)oldlo;
      kout[col] = (key & 0xFFFFFFFF00000000ull) | (ull)oldlo;
    }
  }
}

// Sort 2048 keys descending and emit (order, keep, rec). Proven r11/r12.
__global__ __launch_bounds__(1024) void sort_out(const ull* __restrict__ kout,
                                                 float* __restrict__ out) {
  __shared__ ull keys[N];
  int tid = threadIdx.x;
  keys[tid] = kout[tid];
  keys[tid + 1024] = kout[tid + 1024];
  __syncthreads();
  for (int k = 2; k <= N; k <<= 1) {
    for (int jj = k >> 1; jj > 0; jj >>= 1) {
      int i1 = ((tid & ~(jj - 1)) << 1) | (tid & (jj - 1));
      int i2 = i1 | jj;
      ull a = keys[i1], b = keys[i2];
      bool up = ((i1 & k) == 0);
      if (up ? (a < b) : (a > b)) { keys[i1] = b; keys[i2] = a; }
      __syncthreads();
    }
  }
#pragma unroll
  for (int h = 0; h < 2; h++) {
    int r = tid + 1024 * h;
    ull key = keys[r];
    int col = 2048 - (int)(uint)key;
    float v = __uint_as_float((uint)(key >> 32));
    out[r] = (float)col;
    out[N + r] = ((double)v > 0.001) ? 1.0f : 0.0f;
    out[2 * N + r] = v;
  }
}

// Tiny-ws fallback: on-the-fly dense scan (proven round 8 structure).
__global__ __launch_bounds__(1024) void scan_fly(const float* __restrict__ prep,
                                                 const float* __restrict__ scores,
                                                 float* __restrict__ out) {
  __shared__ float sc[N];
  __shared__ unsigned char sel[N];
  __shared__ float rv[16];
  __shared__ int ri[16];
  int tid = threadIdx.x;
  sc[tid] = scores[tid];
  sc[tid + 1024] = scores[tid + 1024];
  sel[tid] = 0;
  sel[tid + 1024] = 0;
  __syncthreads();
  const float NINF = -__builtin_inff();
  for (int t = 0; t < N; ++t) {
    float v0 = sel[tid] ? NINF : sc[tid];
    float v1 = sel[tid + 1024] ? NINF : sc[tid + 1024];
    float bv; int bi;
    if (v0 >= v1) { bv = v0; bi = tid; } else { bv = v1; bi = tid + 1024; }
#pragma unroll
    for (int off = 32; off > 0; off >>= 1) {
      float ov = __shfl_down(bv, off);
      int oi = __shfl_down(bi, off);
      if (ov > bv || (ov == bv && oi < bi)) { bv = ov; bi = oi; }
    }
    if ((tid & 63) == 0) { rv[tid >> 6] = bv; ri[tid >> 6] = bi; }
    __syncthreads();
    float mv = rv[0]; int mi = ri[0];
#pragma unroll
    for (int k = 1; k < 16; k++) {
      float ov = rv[k]; int oi = ri[k];
      if (ov > mv || (ov == mv && oi < mi)) { mv = ov; mi = oi; }
    }
    if (tid == 0) {
      out[t] = (float)mi;
      out[N + t] = (mv > 0.001f) ? 1.0f : 0.0f;
      out[2 * N + t] = mv;
    }
    if (tid == (mi & 1023)) sel[mi] = 1;
    if (mv > 0.001f) {
      const float* Pm = prep + mi * PSTRIDE;
#pragma unroll
      for (int half = 0; half < 2; half++) {
        int j = tid + half * 1024;
        if (!sel[j]) {
          const float* Pj = prep + j * PSTRIDE;
          float dx = Pm[8] - Pj[8], dy = Pm[9] - Pj[9];
          float rr = Pm[15] + Pj[15] + 1.0f;
          float w = 1.0f;
          if (dx * dx + dy * dy <= rr * rr) w = pair_weight(Pm, Pj);
          sc[j] *= w;
        }
      }
    }
    __syncthreads();
  }
}

extern "C" void kernel_launch(void* const* d_in, const int* in_sizes, int n_in,
                              void* d_out, int out_size, void* d_ws, size_t ws_size,
                              hipStream_t stream) {
  const float* boxes = (const float*)d_in[0];
  const float* scores = (const float*)d_in[1];
  if (n_in >= 2 && in_sizes[0] == N && in_sizes[1] == 5 * N) {
    boxes = (const float*)d_in[1];
    scores = (const float*)d_in[0];
  }
  float* out = (float*)d_out;
  char* ws = (char*)d_ws;
  uint* ccnt = (uint*)(ws + CTR_OFF);
  uint* ecnt = (uint*)(ws + CTR_OFF + 64);
  uint* mcount = (uint*)(ws + CTR_OFF + 128);
  float* prep = (float*)(ws + PREP_OFF);

  if (ws_size >= NEED) {
    uint* cand = (uint*)(ws + CAND_OFF);
    ull* etmp = (ull*)(ws + ETMP_OFF);
    ull* ecsr = (ull*)(ws + ECSR_OFF);
    uint* rinfo = (uint*)(ws + RINF_OFF);
    uint* cursor = (uint*)(ws + CUR_OFF);
    uint* mark = (uint*)(ws + MARK_OFF);
    uint* gcm = (uint*)(ws + GCM_OFF);
    ushort* mlist = (ushort*)(ws + MLIST_OFF);
    ull* kout = (ull*)(ws + KOUT_OFF);
    prep_kernel<<<8, 256, 0, stream>>>(boxes, prep, (uint*)ws, rinfo, mark);
    cand_kernel<<<16384, 256, 0, stream>>>(prep, cand, ccnt);
    weight_kernel<<<4096, 64, 0, stream>>>(prep, cand, ccnt, etmp, ecnt, rinfo, mark);
    csr_fin<<<1, 1024, 0, stream>>>(rinfo, cursor, mark, mlist, gcm, mcount);
    escat_kernel<<<256, 256, 0, stream>>>(etmp, ecnt, cursor, gcm, ecsr);
    scan_sub<<<1, 64, 0, stream>>>(scores, mlist, mcount, rinfo, ecsr, ecnt, mark, kout);
    sort_out<<<1, 1024, 0, stream>>>(kout, out);
  } else {
    prep_kernel<<<8, 256, 0, stream>>>(boxes, prep, (uint*)ws,
                                       (uint*)(ws + 256 + 196608),
                                       (uint*)(ws + 256 + 196608 + 8192));
    scan_fly<<<1, 1024, 0, stream>>>(prep, scores, out);
  }
}

// Round 11
// 1509.033 us; speedup vs baseline: 1.4244x; 1.4244x over previous
//
#include <hip/hip_runtime.h>
#include <math.h>

#define N 2048
#define PSTRIDE 24
#define CCAP (1u << 20)
#define ECAP (1u << 19)
#define ELCAP 12288u  // edges cached in LDS (96KB)

typedef unsigned int uint;
typedef unsigned short ushort;
typedef unsigned long long ull;

// ws layout (bytes):
#define CTR_OFF   0        // ccnt@0, ecnt@64, mcount@128
#define PREP_OFF  256      // 2048*24 f32
#define CAND_OFF  196864   // u32[CCAP]
#define ETMP_OFF  4391168  // u64[ECAP]
#define ECSR_OFF  8585472  // u64[ECAP]
#define RINF_OFF  12779776 // u32[2048]
#define CUR_OFF   12787968 // u32[2048]
#define MARK_OFF  12796160 // u32[2048]
#define GCM_OFF   12804352 // u32[2048]
#define MLIST_OFF 12812544 // ushort[2048]
#define KOUT_OFF  12816640 // u64[2048]
#define NEED      12833024ull

// ---------- DPP wave-64 reductions (wave-uniform call sites ONLY) ----------
// row_shr 1/2/4/8 + row_bcast15/31; result read from lane 63.
__device__ __forceinline__ uint wave_umax_bcast(uint v) {
  int x = (int)v;
  int t;
  t = __builtin_amdgcn_update_dpp(0, x, 0x111, 0xF, 0xF, false); x = (int)((uint)x > (uint)t ? (uint)x : (uint)t);
  t = __builtin_amdgcn_update_dpp(0, x, 0x112, 0xF, 0xF, false); x = (int)((uint)x > (uint)t ? (uint)x : (uint)t);
  t = __builtin_amdgcn_update_dpp(0, x, 0x114, 0xF, 0xF, false); x = (int)((uint)x > (uint)t ? (uint)x : (uint)t);
  t = __builtin_amdgcn_update_dpp(0, x, 0x118, 0xF, 0xF, false); x = (int)((uint)x > (uint)t ? (uint)x : (uint)t);
  t = __builtin_amdgcn_update_dpp(0, x, 0x142, 0xF, 0xF, false); x = (int)((uint)x > (uint)t ? (uint)x : (uint)t);
  t = __builtin_amdgcn_update_dpp(0, x, 0x143, 0xF, 0xF, false); x = (int)((uint)x > (uint)t ? (uint)x : (uint)t);
  return (uint)__builtin_amdgcn_readlane(x, 63);
}

// Per-box precompute + zero counters/rowcnt/mark.
__global__ __launch_bounds__(256) void prep_kernel(const float* __restrict__ boxes,
                                                   float* __restrict__ prep,
                                                   uint* __restrict__ ctrs,
                                                   uint* __restrict__ rowcnt,
                                                   uint* __restrict__ mark) {
#pragma clang fp contract(off)
  int i = blockIdx.x * 256 + threadIdx.x;
  if (blockIdx.x == 0 && threadIdx.x < 3) ctrs[threadIdx.x * 16] = 0u;
  if (i >= N) return;
  rowcnt[i] = 0u;
  mark[i] = 0u;
  float xc = boxes[i * 5 + 0], yc = boxes[i * 5 + 1];
  float w = boxes[i * 5 + 2], h = boxes[i * 5 + 3], th = boxes[i * 5 + 4];
  float t = th * 0.017453292519943295f;
  float c = (float)cos((double)t);
  float s = (float)sin((double)t);
  float w2 = w * 0.5f, h2 = h * 0.5f;
  float lx[4] = {-w2, w2, w2, -w2};
  float ly[4] = {-h2, -h2, h2, h2};
  float* P = prep + i * PSTRIDE;
#pragma unroll
  for (int k = 0; k < 4; k++) {
    P[k * 2 + 0] = (xc + lx[k] * c) - ly[k] * s;
    P[k * 2 + 1] = (yc + lx[k] * s) + ly[k] * c;
  }
  P[8] = xc; P[9] = yc; P[10] = c; P[11] = s; P[12] = w2; P[13] = h2;
  P[14] = w * h;
  P[15] = sqrtf(w2 * w2 + h2 * h2);
  P[16] = w2 * fabsf(c) + h2 * fabsf(s) + 1e-4f;
  P[17] = w2 * fabsf(s) + h2 * fabsf(c) + 1e-4f;
}

// AABB IoU-upper-bound filter (conservative slack, bit-exact prune; proven r12).
__global__ __launch_bounds__(256) void cand_kernel(const float* __restrict__ prep,
                                                   uint* __restrict__ cand,
                                                   uint* __restrict__ ccnt) {
  uint gid = blockIdx.x * 256u + threadIdx.x;
  uint i = gid >> 11, j = gid & 2047u;
  const float* Pi = prep + i * PSTRIDE;
  const float* Pj = prep + j * PSTRIDE;
  float ox = (Pi[16] + Pj[16]) - fabsf(Pi[8] - Pj[8]);
  float oy = (Pi[17] + Pj[17]) - fabsf(Pi[9] - Pj[9]);
  bool keep = (i != j) && (ox > 0.0f) && (oy > 0.0f);
  if (keep) {
    float aa = Pi[14] + Pj[14];
    float iub = fminf(ox * oy, fminf(Pi[14], Pj[14]));
    keep = (13.0f * iub > 2.99f * aa);
  }
  ull m = __ballot(keep);
  if (m == 0ull) return;
  int lane = (int)(threadIdx.x & 63u);
  int leader = __ffsll((long long)m) - 1;
  uint base = 0;
  if (lane == leader) base = atomicAdd(ccnt, (uint)__popcll(m));
  base = (uint)__shfl((int)base, leader);
  if (keep) {
    uint pos = base + (uint)__popcll(m & ((1ull << lane) - 1ull));
    if (pos < CCAP) cand[pos] = (i << 11) | j;
  }
}

// Rotated-rect intersection weight — bit-exact fp32 mirror (proven r8-r12).
__device__ float pair_weight(const float* __restrict__ Pi, const float* __restrict__ Pj) {
#pragma clang fp contract(off)
  float ax[4], ay[4], bx[4], by[4];
#pragma unroll
  for (int k = 0; k < 4; k++) {
    ax[k] = Pi[2 * k]; ay[k] = Pi[2 * k + 1];
    bx[k] = Pj[2 * k]; by[k] = Pj[2 * k + 1];
  }
  float ptsx[24], ptsy[24];
  bool msk[24];
#pragma unroll
  for (int e = 0; e < 4; e++) {
    float Ax = ax[e], Ay = ay[e];
    float BAx = ax[(e + 1) & 3] - Ax, BAy = ay[(e + 1) & 3] - Ay;
#pragma unroll
    for (int f = 0; f < 4; f++) {
      float Cx = bx[f], Cy = by[f];
      float DCx = bx[(f + 1) & 3] - Cx, DCy = by[(f + 1) & 3] - Cy;
      float CAx = Cx - Ax, CAy = Cy - Ay;
      float den = BAx * DCy - BAy * DCx;
      bool dok = fabsf(den) > 1e-12f;
      float dens = dok ? den : 1.0f;
      float t = (CAx * DCy - CAy * DCx) / dens;
      float u = (CAx * BAy - CAy * BAx) / dens;
      int id = e * 4 + f;
      ptsx[id] = Ax + t * BAx;
      ptsy[id] = Ay + t * BAy;
      msk[id] = dok && (t >= 0.0f) && (t <= 1.0f) && (u >= 0.0f) && (u <= 1.0f);
    }
  }
  float xcj = Pj[8], ycj = Pj[9], cj = Pj[10], sj = Pj[11], w2j = Pj[12], h2j = Pj[13];
  float xci = Pi[8], yci = Pi[9], ci = Pi[10], si = Pi[11], w2i = Pi[12], h2i = Pi[13];
#pragma unroll
  for (int k = 0; k < 4; k++) {
    float dx = ax[k] - xcj, dy = ay[k] - ycj;
    float xl = dx * cj + dy * sj;
    float yl = -dx * sj + dy * cj;
    ptsx[16 + k] = ax[k]; ptsy[16 + k] = ay[k];
    msk[16 + k] = (fabsf(xl) <= w2j + 1e-5f) && (fabsf(yl) <= h2j + 1e-5f);
  }
#pragma unroll
  for (int k = 0; k < 4; k++) {
    float dx = bx[k] - xci, dy = by[k] - yci;
    float xl = dx * ci + dy * si;
    float yl = -dx * si + dy * ci;
    ptsx[20 + k] = bx[k]; ptsy[20 + k] = by[k];
    msk[20 + k] = (fabsf(xl) <= w2i + 1e-5f) && (fabsf(yl) <= h2i + 1e-5f);
  }
  int cnt = 0;
  float sx = 0.f, sy = 0.f;
#pragma unroll
  for (int k = 0; k < 24; k++) {
    if (msk[k]) { cnt++; sx += ptsx[k]; sy += ptsy[k]; }
  }
  float fc = (float)(cnt > 1 ? cnt : 1);
  float ctx = sx / fc, cty = sy / fc;
  float ang[32], px[32], py[32];
  int idp[32];
#pragma unroll
  for (int k = 0; k < 24; k++) {
    float rx = ptsx[k] - ctx, ry = ptsy[k] - cty;
    px[k] = rx; py[k] = ry; idp[k] = k;
    ang[k] = msk[k] ? (float)atan2((double)ry, (double)rx) : 1.0e3f;
  }
#pragma unroll
  for (int k = 24; k < 32; k++) { ang[k] = 1.0e30f; px[k] = 0.f; py[k] = 0.f; idp[k] = k; }
#pragma unroll
  for (int k = 2; k <= 32; k <<= 1) {
#pragma unroll
    for (int j = k >> 1; j > 0; j >>= 1) {
#pragma unroll
      for (int x = 0; x < 32; x++) {
        int l = x ^ j;
        if (l > x) {
          bool up = ((x & k) == 0);
          bool gt = (ang[x] > ang[l]) || (ang[x] == ang[l] && idp[x] > idp[l]);
          if (gt == up) {
            float t0 = ang[x]; ang[x] = ang[l]; ang[l] = t0;
            float t1 = px[x]; px[x] = px[l]; px[l] = t1;
            float t2 = py[x]; py[x] = py[l]; py[l] = t2;
            int t3 = idp[x]; idp[x] = idp[l]; idp[l] = t3;
          }
        }
      }
    }
  }
  float term[24];
#pragma unroll
  for (int x = 0; x < 24; x++) {
    int nx = (x + 1 < cnt) ? x + 1 : 0;
    float cr = px[x] * py[nx] - py[x] * px[nx];
    term[x] = (x < cnt) ? cr : 0.0f;
  }
  float r[8];
#pragma unroll
  for (int j = 0; j < 8; j++) r[j] = (term[j] + term[j + 8]) + term[j + 16];
  float ssum = ((r[0] + r[1]) + (r[2] + r[3])) + ((r[4] + r[5]) + (r[6] + r[7]));
  float area = 0.5f * fabsf(ssum);
  float inter = (cnt >= 3) ? area : 0.0f;
  float iou = inter / ((Pi[14] + Pj[14] - inter) + 1e-9f);
  return (iou > 0.3f) ? (1.0f - iou) : 1.0f;
}

// Heavy geometry on candidates (grid-stride); emit sparse edge iff w != 1.
// grid 4096: more resident waves/SIMD hide the dependent bitonic chain.
__global__ __launch_bounds__(64, 2) void weight_kernel(const float* __restrict__ prep,
                                                       const uint* __restrict__ cand,
                                                       const uint* __restrict__ ccnt,
                                                       ull* __restrict__ etmp,
                                                       uint* __restrict__ ecnt,
                                                       uint* __restrict__ rowcnt,
                                                       uint* __restrict__ mark) {
  uint n = *ccnt;
  if (n > CCAP) n = CCAP;
  for (uint idx = blockIdx.x * 64u + threadIdx.x; idx < n; idx += gridDim.x * 64u) {
    uint pk = cand[idx];
    uint i = pk >> 11, j = pk & 2047u;
    float w = pair_weight(prep + i * PSTRIDE, prep + j * PSTRIDE);
    if (w != 1.0f) {
      uint pos = atomicAdd(ecnt, 1u);
      if (pos < ECAP) {
        etmp[pos] = (((ull)__float_as_uint(w)) << 32) | (ull)pk;
        atomicAdd(rowcnt + i, 1u);
        mark[i] = 1u;
        mark[j] = 1u;
      }
    }
  }
}

// CSR finalize (proven r12).
__global__ __launch_bounds__(1024) void csr_fin(uint* __restrict__ rinfo,
                                                uint* __restrict__ cursor,
                                                const uint* __restrict__ mark,
                                                ushort* __restrict__ mlist,
                                                uint* __restrict__ gcm,
                                                uint* __restrict__ mcount) {
  __shared__ uint pre[N];
  __shared__ uint msh;
  int tid = threadIdx.x;
  uint c0 = rinfo[tid], c1 = rinfo[tid + 1024];
  pre[tid] = c0; pre[tid + 1024] = c1;
  if (tid == 0) msh = 0;
  __syncthreads();
  for (int d = 1; d < N; d <<= 1) {
    uint a0 = pre[tid] + ((tid >= d) ? pre[tid - d] : 0);
    uint a1 = pre[tid + 1024] + ((tid + 1024 >= d) ? pre[tid + 1024 - d] : 0);
    __syncthreads();
    pre[tid] = a0; pre[tid + 1024] = a1;
    __syncthreads();
  }
  uint p0 = pre[tid] - c0, p1 = pre[tid + 1024] - c1;
  rinfo[tid] = p0 | (c0 << 20);
  rinfo[tid + 1024] = p1 | (c1 << 20);
  cursor[tid] = p0;
  cursor[tid + 1024] = p1;
  if (mark[tid]) { uint m = atomicAdd(&msh, 1u); mlist[m] = (ushort)tid; gcm[tid] = m; }
  if (mark[tid + 1024]) { uint m = atomicAdd(&msh, 1u); mlist[m] = (ushort)(tid + 1024); gcm[tid + 1024] = m; }
  __syncthreads();
  if (tid == 0) *mcount = msh;
}

// Scatter edges into CSR slots; target stored as member index (grid-stride).
__global__ __launch_bounds__(256) void escat_kernel(const ull* __restrict__ etmp,
                                                    const uint* __restrict__ ecnt,
                                                    uint* __restrict__ cursor,
                                                    const uint* __restrict__ gcm,
                                                    ull* __restrict__ ecsr) {
  uint n = *ecnt;
  if (n > ECAP) n = ECAP;
  for (uint e = blockIdx.x * 256u + threadIdx.x; e < n; e += gridDim.x * 256u) {
    ull ed = etmp[e];
    uint lo = (uint)ed;
    uint i = (lo >> 11) & 2047u, j = lo & 2047u;
    uint pos = atomicAdd(cursor + i, 1u);
    ecsr[pos] = (ed & 0xFFFFFFFF00000000ull) | (ull)gcm[j];
  }
}

// Sequential soft-NMS over members, ONE wave — BATCHED selection, register
// walk with in-walk column seconds + PACKED KEYS (r11 = r10 packing at the
// r9-PROVEN cap 12; r10's cap-20 arrays spilled to scratch: FETCH +48KB,
// VALUBusy 2x, +71% time).
// Key = score<<32 | (2048-col)<<16 | osec<<15 | slot.  Tie order =
// (score, col, ...) — col determines the rest, so argmax tie-break matches
// the reference exactly.  readlane(lo) after the owner ballot yields col,
// slot AND osec => the per-accept readlane(ptop) and ballot(on_second) are
// GONE (cross-lane ops dominate the serial chain — r6/r8/r9 calibration).
// Rebuild tournament carries keys only (no slot arrays).
// Deferred apply (r6 structure; r7's eager pipeline regressed).
// Exactness:
//  - candidates are pre-batch column top-2; live candidate upper-bounds all
//    remaining current values of its column (decays deferred + only shrink).
//    g exact iff its slot untouched by an earlier accept's edges (register
//    ts ballot) — else break; re-surfaces exact next round.
//  - column whose SECOND is accepted is exhausted => batch ends after it.
//  - osec bit is set only in the promoted REGISTER copy (never stored), and
//    only perturbs ordering below the col field => ordering unchanged.
//  - apply in b-order; per-wave in-order DS pipe => per-slot multiply order
//    matches the reference exactly.
__global__ __launch_bounds__(64) void scan_sub(const float* __restrict__ scores,
                                               const ushort* __restrict__ mlist,
                                               const uint* __restrict__ mcount,
                                               const uint* __restrict__ rinfo_g,
                                               const ull* __restrict__ ecsr,
                                               const uint* __restrict__ ecnt,
                                               const uint* __restrict__ mark,
                                               ull* __restrict__ kout) {
#pragma clang fp contract(off)
  __shared__ ull mkey[N];       // column-major member keys: m -> (m&63)*32+(m>>6)
  __shared__ uint rinfo[N];
  __shared__ ull eld[ELCAP];
  const int lane = threadIdx.x;
#pragma unroll
  for (int k = 0; k < 8; k++) {
    int i4 = lane + 64 * k;
    ((uint4*)rinfo)[i4] = ((const uint4*)rinfo_g)[i4];
  }
#pragma unroll
  for (int k = 0; k < 32; k++) mkey[lane + 64 * k] = 0ull;
  // non-member keys straight to kout (output format: score<<32 | (2048-col))
#pragma unroll
  for (int k = 0; k < 32; k++) {
    int col = lane + 64 * k;
    if (!mark[col]) {
      uint b = __float_as_uint(scores[col]);
      kout[col] = (((ull)b) << 32) | (ull)(uint)(2048 - col);
    }
  }
  uint E = *ecnt;
  if (E > ECAP) E = ECAP;
  bool use_lds = (E <= ELCAP);
  if (use_lds) {
    uint n4 = (E + 1) >> 1;  // uint4 count
    for (uint q = (uint)lane; q < n4; q += 64u)
      ((uint4*)eld)[q] = ((const uint4*)ecsr)[q];
  }
  int M = (int)*mcount;
  // fill member keys, PACKED (rotated group order dodges the bank clash)
  for (int g = 0; g < 32; g++) {
    int gp = (g + lane) & 31;
    int m = lane + 64 * gp;
    if (m < M) {
      int col = (int)mlist[m];
      uint b = __float_as_uint(scores[col]);
      uint cm = (uint)lane * 32u + (uint)gp;  // CM(m) == slot
      uint lo = ((uint)(2048 - col) << 16) | cm;
      mkey[cm] = (((ull)b) << 32) | (ull)lo;
    }
  }
  asm volatile("s_waitcnt lgkmcnt(0) vmcnt(0)" ::: "memory");
  ull walk_pk = 0ull;   // lane's active candidate (column max, then second)
  ull wsec = 0ull;      // backup candidate (column second)
  uint myinfo = 0u;     // rinfo of active candidate's box
  uint minfo2 = 0u;     // rinfo of backup candidate's box
  auto rebuild = [&]() {
    const uint base = (uint)lane * 32u;
    ull m[16], s2[16];
#pragma unroll
    for (int k = 0; k < 16; k++) {
      uint i0 = base + (uint)((2 * k + lane) & 31);
      uint i1 = base + (uint)((2 * k + 1 + lane) & 31);
      ull a = mkey[i0], b = mkey[i1];
      bool gt = b > a;
      m[k] = gt ? b : a;
      s2[k] = gt ? a : b;
    }
#pragma unroll
    for (int st = 8; st >= 1; st >>= 1) {
#pragma unroll
      for (int k = 0; k < st; k++) {
        ull m1 = m[k], m2 = m[k + st];
        bool gt = m2 > m1;
        ull mw = gt ? m2 : m1;
        ull ml = gt ? m1 : m2;
        ull sa = s2[k], sb = s2[k + st];
        ull sm = sa > sb ? sa : sb;
        ull sec = ml > sm ? ml : sm;
        m[k] = mw; s2[k] = sec;
      }
    }
    walk_pk = m[0]; wsec = s2[0];
    int pb = 2048 - (int)((uint)walk_pk >> 16);
    myinfo = rinfo[((uint)pb <= 2047u) ? pb : 0];
    int pb2 = 2048 - (int)((uint)wsec >> 16);
    minfo2 = rinfo[((uint)pb2 <= 2047u) ? pb2 : 0];
  };
  rebuild();
  int tdone = 0;
  bool done = false;
  for (int round = 0; round < N; ++round) {
    if (done || tdone >= M) break;
    uint B = 0u;
    bool active = true;
    ull ew_[12];
    uint ts_[12], inf_[12];
    uint vmask = 0u;
#pragma unroll
    for (int b = 0; b < 12; b++) { ew_[b] = 0ull; ts_[b] = 0xFFFFFFFFu; inf_[b] = 0u; }
    // ---- WALK: up to 12 accepts; 32-bit fast-path argmax + lazy ts ----
#pragma unroll
    for (int b = 0; b < 12; b++) {
      if (active) {
        uint hi = (uint)(walk_pk >> 32);
        uint ghi = wave_umax_bcast(hi);
        // (double)score > 0.001  <=>  bits > 0x3A83126E for nonneg f32 in [0,1)
        if (!(ghi > 0x3A83126Eu)) {
          done = true; active = false;
        } else {
          ull bal = __ballot(hi == ghi);
          int ol; uint glo;
          if (__popcll(bal) == 1) {      // common: unique hi owner
            ol = __ffsll((long long)bal) - 1;
            glo = (uint)__builtin_amdgcn_readlane((int)(uint)walk_pk, ol);
          } else {                        // rare: exact lo tie-break
            uint cnd = (hi == ghi) ? (uint)walk_pk : 0u;
            glo = wave_umax_bcast(cnd);
            bal = __ballot((hi == ghi) && ((uint)walk_pk == glo));
            ol = __ffsll((long long)bal) - 1;
          }
          // lazy ts for accept b-1: edge data arrived during this reduction
          if (b > 0) {
            uint mtp = (uint)ew_[b - 1] & 2047u;
            ts_[b - 1] = ((mtp & 63u) << 5) | (mtp >> 6);
          }
          uint slot = glo & 0x7FFu;               // packed: no readlane needed
          bool osec = (glo & 0x8000u) != 0u;      // packed: no ballot needed
          uint info = (uint)__builtin_amdgcn_readlane((int)myinfo, ol);
          bool anyhit = false;
#pragma unroll
          for (int p = 0; p < 12; p++) {
            if (p < b) anyhit = anyhit || ((((vmask >> p) & 1u) != 0u) && (ts_[p] == slot));
          }
          if (__ballot(anyhit) != 0ull) {
            active = false;  // value stale-high; surfaces correctly next round
          } else {
            // ---- ACCEPT b ----
            uint oldlo = glo >> 16;               // 2048-col (osec/slot shifted out)
            int bj = 2048 - (int)oldlo;
            if (lane == 0) {
              kout[bj] = (((ull)ghi) << 32) | (ull)oldlo;
              mkey[slot] = 0ull;
            }
            if (lane == ol) {  // promote to column second; tag osec in-register
              walk_pk = wsec | 0x8000ull;
              myinfo = minfo2;
            }
            uint ptr = info & 0xFFFFFu;
            uint deg = info >> 20;
            bool vld = (uint)lane < deg;
            ull ed = 0ull;
            if (vld) ed = use_lds ? eld[ptr + (uint)lane] : ecsr[ptr + (uint)lane];
            ew_[b] = ed;      // ts computed lazily at next accept
            inf_[b] = info;
            vmask |= (vld ? 1u : 0u) << b;
            B = (uint)b + 1u;
            tdone++;
            if (deg > 64u) active = false;  // tail targets unchecked: end batch
            if (osec) active = false;       // column exhausted: end batch
          }
        }
      }
    }
    // ---- APPLY (bit-exact, b-order; DS in-order serializes shared slots) ----
#pragma unroll
    for (int b = 0; b < 12; b++) {
      if ((uint)b < B) {
        if ((vmask >> b) & 1u) {
          uint mt = (uint)ew_[b] & 2047u;
          uint ts = ((mt & 63u) << 5) | (mt >> 6);
          float w = __uint_as_float((uint)(ew_[b] >> 32));
          ull ok = mkey[ts];
          float nv = __uint_as_float((uint)(ok >> 32)) * w;
          mkey[ts] = (((ull)__float_as_uint(nv)) << 32) | (ok & 0xFFFFFFFFull);
        }
        uint ptr = inf_[b] & 0xFFFFFu, deg = inf_[b] >> 20;
        for (uint e = 64u + (uint)lane; e < deg; e += 64u) {
          ull ee = use_lds ? eld[ptr + e] : ecsr[ptr + e];
          uint mt = (uint)ee & 2047u;
          uint ts = ((mt & 63u) << 5) | (mt >> 6);
          float w = __uint_as_float((uint)(ee >> 32));
          ull ok = mkey[ts];
          float nv = __uint_as_float((uint)(ok >> 32)) * w;
          mkey[ts] = (((ull)__float_as_uint(nv)) << 32) | (ok & 0xFFFFFFFFull);
        }
      }
    }
    if (done || tdone >= M) break;
    asm volatile("s_waitcnt lgkmcnt(0)" ::: "memory");
    rebuild();
  }
  asm volatile("s_waitcnt lgkmcnt(0)" ::: "memory");
  // flush remaining (unselected) members; unpack col, emit output format
#pragma unroll
  for (int g = 0; g < 32; g++) {
    ull key = mkey[lane + 64 * g];
    if (key != 0ull) {
      uint oldlo = (uint)key >> 16;  // 2048-col
      int col = 2048 - (int)oldlo;
      kout[col] = (key & 0xFFFFFFFF00000000ull) | (ull)oldlo;
    }
  }
}

// Sort 2048 keys descending and emit (order, keep, rec). Proven r11/r12.
__global__ __launch_bounds__(1024) void sort_out(const ull* __restrict__ kout,
                                                 float* __restrict__ out) {
  __shared__ ull keys[N];
  int tid = threadIdx.x;
  keys[tid] = kout[tid];
  keys[tid + 1024] = kout[tid + 1024];
  __syncthreads();
  for (int k = 2; k <= N; k <<= 1) {
    for (int jj = k >> 1; jj > 0; jj >>= 1) {
      int i1 = ((tid & ~(jj - 1)) << 1) | (tid & (jj - 1));
      int i2 = i1 | jj;
      ull a = keys[i1], b = keys[i2];
      bool up = ((i1 & k) == 0);
      if (up ? (a < b) : (a > b)) { keys[i1] = b; keys[i2] = a; }
      __syncthreads();
    }
  }
#pragma unroll
  for (int h = 0; h < 2; h++) {
    int r = tid + 1024 * h;
    ull key = keys[r];
    int col = 2048 - (int)(uint)key;
    float v = __uint_as_float((uint)(key >> 32));
    out[r] = (float)col;
    out[N + r] = ((double)v > 0.001) ? 1.0f : 0.0f;
    out[2 * N + r] = v;
  }
}

// Tiny-ws fallback: on-the-fly dense scan (proven round 8 structure).
__global__ __launch_bounds__(1024) void scan_fly(const float* __restrict__ prep,
                                                 const float* __restrict__ scores,
                                                 float* __restrict__ out) {
  __shared__ float sc[N];
  __shared__ unsigned char sel[N];
  __shared__ float rv[16];
  __shared__ int ri[16];
  int tid = threadIdx.x;
  sc[tid] = scores[tid];
  sc[tid + 1024] = scores[tid + 1024];
  sel[tid] = 0;
  sel[tid + 1024] = 0;
  __syncthreads();
  const float NINF = -__builtin_inff();
  for (int t = 0; t < N; ++t) {
    float v0 = sel[tid] ? NINF : sc[tid];
    float v1 = sel[tid + 1024] ? NINF : sc[tid + 1024];
    float bv; int bi;
    if (v0 >= v1) { bv = v0; bi = tid; } else { bv = v1; bi = tid + 1024; }
#pragma unroll
    for (int off = 32; off > 0; off >>= 1) {
      float ov = __shfl_down(bv, off);
      int oi = __shfl_down(bi, off);
      if (ov > bv || (ov == bv && oi < bi)) { bv = ov; bi = oi; }
    }
    if ((tid & 63) == 0) { rv[tid >> 6] = bv; ri[tid >> 6] = bi; }
    __syncthreads();
    float mv = rv[0]; int mi = ri[0];
#pragma unroll
    for (int k = 1; k < 16; k++) {
      float ov = rv[k]; int oi = ri[k];
      if (ov > mv || (ov == mv && oi < mi)) { mv = ov; mi = oi; }
    }
    if (tid == 0) {
      out[t] = (float)mi;
      out[N + t] = (mv > 0.001f) ? 1.0f : 0.0f;
      out[2 * N + t] = mv;
    }
    if (tid == (mi & 1023)) sel[mi] = 1;
    if (mv > 0.001f) {
      const float* Pm = prep + mi * PSTRIDE;
#pragma unroll
      for (int half = 0; half < 2; half++) {
        int j = tid + half * 1024;
        if (!sel[j]) {
          const float* Pj = prep + j * PSTRIDE;
          float dx = Pm[8] - Pj[8], dy = Pm[9] - Pj[9];
          float rr = Pm[15] + Pj[15] + 1.0f;
          float w = 1.0f;
          if (dx * dx + dy * dy <= rr * rr) w = pair_weight(Pm, Pj);
          sc[j] *= w;
        }
      }
    }
    __syncthreads();
  }
}

extern "C" void kernel_launch(void* const* d_in, const int* in_sizes, int n_in,
                              void* d_out, int out_size, void* d_ws, size_t ws_size,
                              hipStream_t stream) {
  const float* boxes = (const float*)d_in[0];
  const float* scores = (const float*)d_in[1];
  if (n_in >= 2 && in_sizes[0] == N && in_sizes[1] == 5 * N) {
    boxes = (const float*)d_in[1];
    scores = (const float*)d_in[0];
  }
  float* out = (float*)d_out;
  char* ws = (char*)d_ws;
  uint* ccnt = (uint*)(ws + CTR_OFF);
  uint* ecnt = (uint*)(ws + CTR_OFF + 64);
  uint* mcount = (uint*)(ws + CTR_OFF + 128);
  float* prep = (float*)(ws + PREP_OFF);

  if (ws_size >= NEED) {
    uint* cand = (uint*)(ws + CAND_OFF);
    ull* etmp = (ull*)(ws + ETMP_OFF);
    ull* ecsr = (ull*)(ws + ECSR_OFF);
    uint* rinfo = (uint*)(ws + RINF_OFF);
    uint* cursor = (uint*)(ws + CUR_OFF);
    uint* mark = (uint*)(ws + MARK_OFF);
    uint* gcm = (uint*)(ws + GCM_OFF);
    ushort* mlist = (ushort*)(ws + MLIST_OFF);
    ull* kout = (ull*)(ws + KOUT_OFF);
    prep_kernel<<<8, 256, 0, stream>>>(boxes, prep, (uint*)ws, rinfo, mark);
    cand_kernel<<<16384, 256, 0, stream>>>(prep, cand, ccnt);
    weight_kernel<<<4096, 64, 0, stream>>>(prep, cand, ccnt, etmp, ecnt, rinfo, mark);
    csr_fin<<<1, 1024, 0, stream>>>(rinfo, cursor, mark, mlist, gcm, mcount);
    escat_kernel<<<256, 256, 0, stream>>>(etmp, ecnt, cursor, gcm, ecsr);
    scan_sub<<<1, 64, 0, stream>>>(scores, mlist, mcount, rinfo, ecsr, ecnt, mark, kout);
    sort_out<<<1, 1024, 0, stream>>>(kout, out);
  } else {
    prep_kernel<<<8, 256, 0, stream>>>(boxes, prep, (uint*)ws,
                                       (uint*)(ws + 256 + 196608),
                                       (uint*)(ws + 256 + 196608 + 8192));
    scan_fly<<<1, 1024, 0, stream>>>(prep, scores, out);
  }
}